// Round 9
// baseline (498.223 us; speedup 1.0000x reference)
//
#include <hip/hip_runtime.h>
#include <hip/hip_bf16.h>
#include <cstdint>
#include <cstddef>

typedef __bf16 bf16_t;
typedef __bf16 bf16x4 __attribute__((ext_vector_type(4)));
typedef __bf16 bf16x8 __attribute__((ext_vector_type(8)));
typedef float  f32x4  __attribute__((ext_vector_type(4)));

#define NB   16
#define NC   256
#define NO   256
#define SD   512
#define NPIX 4096   // 64*64
#define CPAD 36     // B LDS stride: 72B rows -> 8B ops conflict-free (r1/r4/r7: 0)

// workspace layout (bytes)
#define WS_S   0        // s   [16][256] f32  (16 KB)
#define WS_WSQ 32768    // wsq [256][256] f32 (256 KB)
#define WS_WT  294912   // wT  [9][256][256] bf16 (1.125 MB)

// ---------------------------------------------------------------------------
// prep1: blocks 0..15  -> s[b,i]   = style[b,:] . mod_w[i,:] + mod_b[i]
//        blocks 16..271-> wsq[o,i] = sum_t w[o,i,t]^2 ; wT[t][o][i] = bf16(w[o][i][t])
// ---------------------------------------------------------------------------
__global__ __launch_bounds__(256) void prep1(
    const float* __restrict__ style, const float* __restrict__ weight,
    const float* __restrict__ mod_w, const float* __restrict__ mod_b,
    float* __restrict__ s_buf, float* __restrict__ wsq, bf16_t* __restrict__ wT)
{
    const int blk = blockIdx.x;
    const int tid = threadIdx.x;
    if (blk < 16) {
        const int b = blk, i = tid;
        const float* st = style + b * SD;
        const float* mw = mod_w + i * SD;
        float acc = 0.f;
        for (int k = 0; k < SD; k += 4) {
            float4 a = *(const float4*)(st + k);
            float4 c = *(const float4*)(mw + k);
            acc += a.x * c.x + a.y * c.y + a.z * c.z + a.w * c.w;
        }
        s_buf[b * NC + i] = acc + mod_b[i];
    } else {
        const int o = blk - 16, i = tid;
        const float* wp = weight + (o * NC + i) * 9;
        float q = 0.f;
        #pragma unroll
        for (int t = 0; t < 9; ++t) {
            float v = wp[t];
            q += v * v;
            wT[t * (NO * NC) + o * NC + i] = (bf16_t)v;
        }
        wsq[o * NC + i] = q;
    }
}

// ---------------------------------------------------------------------------
// conv: implicit-GEMM. Block: 128 out_ch x 128 positions (2 image rows);
// 4 waves (256 thr), each 64x64 via 4x4 frags of mfma_f32_16x16x32_bf16.
//
// WHY A-IN-REGISTERS: LDS-pipe arithmetic (r8 post-mortem). With A in LDS,
// per chunk-block LDS traffic = A-read 144KB + B-read 144KB + A-DMA-write
// 72KB + B-write 16KB ~ 376KB ~ 4400 cyc @85B/cyc vs 2794 cyc of matrix
// work -> LDS-BW-bound at MfmaUtil ~21% regardless of schedule (r0/r4/r7/r8
// all identical). A in VGPRs (L2-resident wT, 52 B/cyc/CU < 135 L2 ceiling)
// removes 216KB -> matrix pipe becomes the binding resource.
// Prefetch: 3-tap register groups, double-buffered (named arrays, constant
// indices only -- rule #20), ~773 cyc/wave of MFMA cover per group load
// (r1's 1-tap variant had 78 cyc -> L2-latency-serial; that was its bug).
// B (x*s): single LDS buffer, CPAD=36 + 8B ops (0 conflicts, measured).
// Barriers: 2 per chunk (B lifecycle only).
// d (demod): fused epilogue from L2-resident wsq.
// ---------------------------------------------------------------------------
__global__ __launch_bounds__(256, 2) void conv_mfma(
    const float* __restrict__ x,
    const bf16_t* __restrict__ wT,
    const float* __restrict__ s_buf,
    const float* __restrict__ wsq,
    float* __restrict__ out)
{
    __shared__ bf16_t lds_b[4 * 64 * CPAD];     // 18 KB: B (x*s), single buffer

    const int tid   = threadIdx.x;
    const int lane  = tid & 63;
    const int wv    = tid >> 6;
    const int wo    = wv >> 1;       // wave o-half
    const int wp    = wv & 1;        // wave p-half (= image row within tile)
    const int pt    = blockIdx.x;    // 0..31 position tiles (2 rows each)
    const int o0    = blockIdx.y * 128;
    const int batch = blockIdx.z;
    const int row0  = pt * 2;

    const int l15 = lane & 15;
    const int k0  = (lane >> 4) * 8;

    const int colB = tid & 63;       // staging: column
    const int cgrp = tid >> 6;       // staging: channel group (8 ch each)

    f32x4 acc[4][4];
    #pragma unroll
    for (int i = 0; i < 4; ++i)
        #pragma unroll
        for (int j = 0; j < 4; ++j) {
            f32x4 z = {0.f, 0.f, 0.f, 0.f};
            acc[i][j] = z;
        }

    bf16x8 bzero;
    #pragma unroll
    for (int j = 0; j < 8; ++j) bzero[j] = (bf16_t)0.f;

    const size_t TSTR = (size_t)NO * NC;  // 65536 elems per tap plane
    // per-lane A row base: o-row (o0 + wo*64 + l15), k-slice k0.
    // lanes {l15, kg=0..3} read contiguous 64B of one wT row -> full L2 lines.
    const bf16_t* aBase = wT + (size_t)(o0 + wo * 64 + l15) * NC + k0;

    // A register double buffer: two 3-tap groups, 12 bf16x8 each, NAMED arrays
    bf16x8 af0[12], af1[12];

// issue the 12 global loads for taps (T0..T0+2), chunk channels IC, into DST.
// sched_barrier(0) pins the issue point (loads must not sink below the MFMAs
// that provide their latency cover).
#define LOADG(DST, T0, IC)                                                     \
    do {                                                                       \
        _Pragma("unroll")                                                      \
        for (int t_ = 0; t_ < 3; ++t_) {                                       \
            _Pragma("unroll")                                                  \
            for (int of_ = 0; of_ < 4; ++of_)                                  \
                DST[t_ * 4 + of_] = *(const bf16x8*)(                          \
                    aBase + (size_t)((T0) + t_) * TSTR + (IC) + of_ * 16 * NC);\
        }                                                                      \
        __builtin_amdgcn_sched_barrier(0);                                     \
    } while (0)

// compute one 3-tap group (kernel row KH) held in named group AG: 48 MFMAs
#define COMPG(AG, KH)                                                          \
    do {                                                                       \
        const int r_ = wp + (KH);                                              \
        __builtin_amdgcn_s_setprio(1);                                         \
        _Pragma("unroll")                                                      \
        for (int kw_ = 0; kw_ < 3; ++kw_) {                                    \
            bf16x8 bfr_[4];                                                    \
            _Pragma("unroll")                                                  \
            for (int nf_ = 0; nf_ < 4; ++nf_) {                                \
                const int c_ = nf_ * 16 + l15 + kw_ - 1;                       \
                if ((unsigned)c_ < 64u) {                                      \
                    const bf16_t* p_ = &lds_b[(r_ * 64 + c_) * CPAD + k0];     \
                    bf16x4 lo_ = *(const bf16x4*)p_;                           \
                    bf16x4 hi_ = *(const bf16x4*)(p_ + 4);                     \
                    bfr_[nf_] = __builtin_shufflevector(                       \
                        lo_, hi_, 0, 1, 2, 3, 4, 5, 6, 7);                     \
                } else {                                                       \
                    bfr_[nf_] = bzero;                                         \
                }                                                              \
            }                                                                  \
            _Pragma("unroll")                                                  \
            for (int of_ = 0; of_ < 4; ++of_) {                                \
                _Pragma("unroll")                                              \
                for (int nf_ = 0; nf_ < 4; ++nf_)                              \
                    acc[of_][nf_] = __builtin_amdgcn_mfma_f32_16x16x32_bf16(   \
                        AG[kw_ * 4 + of_], bfr_[nf_], acc[of_][nf_], 0, 0, 0); \
            }                                                                  \
        }                                                                      \
        __builtin_amdgcn_s_setprio(0);                                         \
    } while (0)

    // ---- B staging split: XLOAD (issue global loads) / BWRITE (convert+LDS) ----
    float vx[4][8];
    float sv[8];
    auto XLOAD = [&](int ic0) {
        const float* sp = s_buf + batch * NC + ic0 + cgrp * 8;
        float4 sa = *(const float4*)sp;
        float4 sb = *(const float4*)(sp + 4);
        sv[0]=sa.x; sv[1]=sa.y; sv[2]=sa.z; sv[3]=sa.w;
        sv[4]=sb.x; sv[5]=sb.y; sv[6]=sb.z; sv[7]=sb.w;
        const float* xbase = x + (size_t)(batch * NC + ic0 + cgrp * 8) * NPIX + colB;
        #pragma unroll
        for (int r = 0; r < 4; ++r) {
            const int gy = row0 - 1 + r;
            const bool valid = ((unsigned)gy < 64u);   // block-uniform
            const float* rp = xbase + gy * 64;
            #pragma unroll
            for (int j = 0; j < 8; ++j)
                vx[r][j] = valid ? rp[j * NPIX] : 0.f;
        }
    };
    auto BWRITE = [&]() {
        #pragma unroll
        for (int r = 0; r < 4; ++r) {
            const int lbase = (r * 64 + colB) * CPAD + cgrp * 8;
            #pragma unroll
            for (int half = 0; half < 2; ++half) {
                union { bf16_t h[4]; uint2 u; } pk;
                #pragma unroll
                for (int j = 0; j < 4; ++j)
                    pk.h[j] = (bf16_t)(vx[r][half * 4 + j] * sv[half * 4 + j]);
                *(uint2*)&lds_b[lbase + half * 4] = pk.u;   // 8B aligned, conflict-free
            }
        }
    };

// one chunk. On entry A0_ holds this chunk's taps 0-2; on exit (CH<7)
// A1_ holds next chunk's taps 0-2 and lds_b holds next chunk's B.
// x-loads issue BEFORE the A-loads so BWRITE's implicit wait leaves the
// 12 newer A-loads in flight (in-order vmcnt retirement -> vmcnt(12)).
#define CHUNK_BODY(CH, A0_, A1_)                                               \
    do {                                                                       \
        const int ic_ = (CH) * 32;                                             \
        LOADG(A1_, 3, ic_);              /* taps 3-5; cover: COMPG below */    \
        COMPG(A0_, 0);                                                         \
        LOADG(A0_, 6, ic_);              /* taps 6-8 */                        \
        COMPG(A1_, 1);                                                         \
        if ((CH) < 7) {                                                        \
            XLOAD(ic_ + 32);             /* next B (HBM, longest latency) */   \
            LOADG(A1_, 0, ic_ + 32);     /* next chunk taps 0-2 */             \
        }                                                                      \
        COMPG(A0_, 2);                                                         \
        if ((CH) < 7) {                                                        \
            __builtin_amdgcn_s_barrier();   /* all waves done reading lds_b */ \
            BWRITE();                        /* waits x-loads, not A-loads */  \
            asm volatile("s_waitcnt lgkmcnt(0)" ::: "memory");                 \
            __builtin_amdgcn_sched_barrier(0);                                 \
            __builtin_amdgcn_s_barrier();   /* lds_b ready for next chunk */   \
        }                                                                      \
    } while (0)

    // ---- prologue: A taps 0-2 of chunk 0; B chunk 0 ----
    LOADG(af0, 0, 0);
    XLOAD(0);
    BWRITE();                                    // no prior readers
    __syncthreads();

    #pragma unroll 1
    for (int c2 = 0; c2 < 4; ++c2) {
        CHUNK_BODY(2 * c2,     af0, af1);        // even chunk: G0 in af0
        CHUNK_BODY(2 * c2 + 1, af1, af0);        // odd  chunk: G0 in af1
    }

    // ---- demod d for this block's 128 o's (fused prep2) ----
    __syncthreads();                             // lds_b reads done; reuse as d_sh
    float* d_sh = (float*)&lds_b[0];
    {
        const int ol   = tid >> 1;
        const int half = tid & 1;
        const float* wq = wsq + (size_t)(o0 + ol) * NC + half * 128;
        const float* sb = s_buf + batch * NC + half * 128;
        float sum = 0.f;
        #pragma unroll 4
        for (int i = 0; i < 128; i += 4) {
            float4 w4 = *(const float4*)(wq + i);
            float4 s4 = *(const float4*)(sb + i);
            sum += w4.x * s4.x * s4.x + w4.y * s4.y * s4.y
                 + w4.z * s4.z * s4.z + w4.w * s4.w * s4.w;
        }
        sum += __shfl_xor(sum, 1);
        if (half == 0) d_sh[ol] = rsqrtf(sum + 1e-8f);
    }
    __syncthreads();

    // ---- epilogue: y = acc * d[b,o], store fp32 ----
    const int p_base = pt * 128 + wp * 64;
    #pragma unroll
    for (int of = 0; of < 4; ++of) {
        #pragma unroll
        for (int rg = 0; rg < 4; ++rg) {
            const int o_l = wo * 64 + of * 16 + (lane >> 4) * 4 + rg;
            const float dv = d_sh[o_l];
            const size_t obase = (size_t)(batch * NO + o0 + o_l) * NPIX;
            #pragma unroll
            for (int nf = 0; nf < 4; ++nf) {
                const int p_g = p_base + nf * 16 + l15;
                out[obase + p_g] = acc[of][nf][rg] * dv;
            }
        }
    }
#undef LOADG
#undef COMPG
#undef CHUNK_BODY
}

// ---------------------------------------------------------------------------
extern "C" void kernel_launch(void* const* d_in, const int* in_sizes, int n_in,
                              void* d_out, int out_size, void* d_ws, size_t ws_size,
                              hipStream_t stream)
{
    const float* x      = (const float*)d_in[0];
    const float* style  = (const float*)d_in[1];
    const float* weight = (const float*)d_in[2];
    const float* mod_w  = (const float*)d_in[3];
    const float* mod_b  = (const float*)d_in[4];
    float* out = (float*)d_out;

    char* ws = (char*)d_ws;
    float*  s_buf = (float*)(ws + WS_S);
    float*  wsq   = (float*)(ws + WS_WSQ);
    bf16_t* wT    = (bf16_t*)(ws + WS_WT);

    hipLaunchKernelGGL(prep1, dim3(272), dim3(256), 0, stream,
                       style, weight, mod_w, mod_b, s_buf, wsq, wT);
    hipLaunchKernelGGL(conv_mfma, dim3(32, 2, 16), dim3(256), 0, stream,
                       x, wT, s_buf, wsq, out);
}

// Round 10
// 383.645 us; speedup vs baseline: 1.2987x; 1.2987x over previous
//
#include <hip/hip_runtime.h>
#include <hip/hip_bf16.h>
#include <cstdint>
#include <cstddef>

typedef __bf16 bf16_t;
typedef __bf16 bf16x4 __attribute__((ext_vector_type(4)));
typedef __bf16 bf16x8 __attribute__((ext_vector_type(8)));
typedef float  f32x4  __attribute__((ext_vector_type(4)));

#define NB   16
#define NC   256
#define NO   256
#define SD   512
#define NPIX 4096   // 64*64
#define CPAD 36     // B LDS stride: 72B rows -> 8B ops conflict-free (r1/r4/r7: 0)

// workspace layout (bytes)
#define WS_S   0        // s   [16][256] f32  (16 KB)
#define WS_WSQ 32768    // wsq [256][256] f32 (256 KB)
#define WS_WT  294912   // wT  [9][256][256] bf16 (1.125 MB)

// ---------------------------------------------------------------------------
// prep1: blocks 0..15  -> s[b,i]   = style[b,:] . mod_w[i,:] + mod_b[i]
//        blocks 16..271-> wsq[o,i] = sum_t w[o,i,t]^2 ; wT[t][o][i] = bf16(w[o][i][t])
// ---------------------------------------------------------------------------
__global__ __launch_bounds__(256) void prep1(
    const float* __restrict__ style, const float* __restrict__ weight,
    const float* __restrict__ mod_w, const float* __restrict__ mod_b,
    float* __restrict__ s_buf, float* __restrict__ wsq, bf16_t* __restrict__ wT)
{
    const int blk = blockIdx.x;
    const int tid = threadIdx.x;
    if (blk < 16) {
        const int b = blk, i = tid;
        const float* st = style + b * SD;
        const float* mw = mod_w + i * SD;
        float acc = 0.f;
        for (int k = 0; k < SD; k += 4) {
            float4 a = *(const float4*)(st + k);
            float4 c = *(const float4*)(mw + k);
            acc += a.x * c.x + a.y * c.y + a.z * c.z + a.w * c.w;
        }
        s_buf[b * NC + i] = acc + mod_b[i];
    } else {
        const int o = blk - 16, i = tid;
        const float* wp = weight + (o * NC + i) * 9;
        float q = 0.f;
        #pragma unroll
        for (int t = 0; t < 9; ++t) {
            float v = wp[t];
            q += v * v;
            wT[t * (NO * NC) + o * NC + i] = (bf16_t)v;
        }
        wsq[o * NC + i] = q;
    }
}

// ---------------------------------------------------------------------------
// conv: implicit-GEMM, 256-SQUARE-CLASS GEOMETRY (m198/m201 regime).
// Block: 256 out_ch x 256 positions (4 image rows), 512 thr = 8 waves,
// wave = 128o x 64pos (one image row, one o-half) via 8x4 frags of
// mfma_f32_16x16x32_bf16 -> acc 8x4 f32x4 = 128 AGPR.
// Grid = 16 pt x 16 batch = 256 blocks = EXACTLY 1/CU: no generations.
//
// WHY: r0-r8 all pinned at 21% regardless of barrier count, prefetch depth,
// occupancy -> the serial stage->wait->compute->barrier phase STRUCTURE at
// 128^2 tile is the governor (m233: ~72% overhead in that class; escape is
// the bigger-tile deeper-phase regime, m198/m201). This port: 2x MFMA per
// phase (96/wave), 8x fewer barriers/FLOP, A staged once per CU (was 4x),
// +25% FLOP per LDS byte.
//
// A: global_load_lds w=16, two 3-tap super-buffers (48 KB each, kgrp-major,
//    0-conflict layout), counted vmcnt(6) per phase -- r7's verified engine,
//    scaled to 256 rows.
// B: 6 rows x 64 cols x 32 ch, CPAD=36 single buffer (verified 0-conflict).
// d: fused epilogue from L2-resident wsq.
// ---------------------------------------------------------------------------
__device__ __forceinline__ void stage_a3(const bf16_t* __restrict__ wT_base,
                                         int tap0, int ic0, bf16_t* dst, int tid)
{
    #pragma unroll
    for (int t = 0; t < 3; ++t) {
        const bf16_t* wt = wT_base + (size_t)(tap0 + t) * (NO * NC);
        #pragma unroll
        for (int it = 0; it < 2; ++it) {
            int s = it * 512 + tid;              // 1024 16B segments/tap
            // s -> (kgrp = s>>8, row = s&255); LDS dest linear (rule #21)
            const bf16_t* g = wt + (s & 255) * NC + ic0 + (s >> 8) * 8;
            __builtin_amdgcn_global_load_lds(
                (const __attribute__((address_space(1))) void*)g,
                (__attribute__((address_space(3))) void*)(dst + t * 8192 + s * 8),
                16, 0, 0);
        }
    }
}

__global__ __launch_bounds__(512, 2) void conv_mfma(
    const float* __restrict__ x,
    const bf16_t* __restrict__ wT,
    const float* __restrict__ s_buf,
    const float* __restrict__ wsq,
    float* __restrict__ out)
{
    __shared__ bf16_t lds_a[2][3 * 8192];       // 96 KB: two 3-tap supers, kgrp-major
    __shared__ bf16_t lds_b[6 * 64 * CPAD];     // 27 KB: B (x*s), 6 rows (4 + halo)

    const int tid   = threadIdx.x;
    const int lane  = tid & 63;
    const int wqv   = tid >> 6;      // wave 0..7
    const int wo    = wqv & 1;       // o-half (128 ch)
    const int wp    = wqv >> 1;      // image row within tile (0..3)
    const int pt    = blockIdx.x;    // 0..15 position tiles (4 rows each)
    const int batch = blockIdx.z;
    const int row0  = pt * 4;

    const int l15 = lane & 15;
    const int kg  = lane >> 4;       // k-group 0..3
    const int k0  = kg * 8;

    const int colB = tid & 63;       // staging: column
    const int cgrp = tid >> 6;       // staging: channel group (4 ch each)

    f32x4 acc[8][4];
    #pragma unroll
    for (int i = 0; i < 8; ++i)
        #pragma unroll
        for (int j = 0; j < 4; ++j) {
            f32x4 z = {0.f, 0.f, 0.f, 0.f};
            acc[i][j] = z;
        }

    bf16x8 bzero;
    #pragma unroll
    for (int j = 0; j < 8; ++j) bzero[j] = (bf16_t)0.f;

    bf16_t* lds_a0 = &lds_a[0][0];
    #define SUPER(idx) (lds_a0 + (size_t)((idx) & 1) * (3 * 8192))

    // ---- B staging: XLOAD (issue 24 global loads) / BWRITE (convert+LDS) ----
    float vx[6][4];
    float sv[4];
    auto XLOAD = [&](int ic0) {
        const float* sp = s_buf + batch * NC + ic0 + cgrp * 4;
        float4 sa = *(const float4*)sp;
        sv[0] = sa.x; sv[1] = sa.y; sv[2] = sa.z; sv[3] = sa.w;
        const float* xbase = x + (size_t)(batch * NC + ic0 + cgrp * 4) * NPIX + colB;
        #pragma unroll
        for (int r = 0; r < 6; ++r) {
            const int gy = row0 - 1 + r;
            const bool valid = ((unsigned)gy < 64u);   // block-uniform
            const float* rp = xbase + gy * 64;
            #pragma unroll
            for (int j = 0; j < 4; ++j)
                vx[r][j] = valid ? rp[j * NPIX] : 0.f;
        }
    };
    auto BWRITE = [&]() {
        #pragma unroll
        for (int r = 0; r < 6; ++r) {
            union { bf16_t h[4]; uint2 u; } pk;
            #pragma unroll
            for (int j = 0; j < 4; ++j)
                pk.h[j] = (bf16_t)(vx[r][j] * sv[j]);
            // byte = (r*64+colB)*72 + cgrp*8: 8B aligned, verified 0-conflict
            *(uint2*)&lds_b[(r * 64 + colB) * CPAD + cgrp * 4] = pk.u;
        }
    };

    // ---- prologue: chunk 0 taps 0-2 into super 0; B chunk 0 ----
    stage_a3(wT, 0, 0, SUPER(0), tid);
    XLOAD(0);
    BWRITE();
    __syncthreads();    // full drain: taps 0-2 landed, B ready, invariant set

    #pragma unroll 1
    for (int ch = 0; ch < 8; ++ch) {
        const int ic0 = ch * 32;

        #pragma unroll
        for (int i = 0; i < 3; ++i) {        // phase i computes kh = i, taps 3i..3i+2
            const bf16_t* cur = SUPER(ch + i);
            bf16_t* nxt = SUPER(ch + i + 1);

            if (i < 2) {
                stage_a3(wT, 3 * (i + 1), ic0, nxt, tid);           // next phase
                asm volatile("s_waitcnt vmcnt(6)" ::: "memory");    // this phase landed
            } else if (ch < 7) {
                stage_a3(wT, 0, ic0 + 32, nxt, tid);                // next chunk taps 0-2
                asm volatile("s_waitcnt vmcnt(6)" ::: "memory");
            } else {
                asm volatile("s_waitcnt vmcnt(0)" ::: "memory");    // final phase
            }
            __builtin_amdgcn_sched_barrier(0);

            if (i == 2 && ch < 7)
                XLOAD(ic0 + 32);             // x-loads stay un-waited past vmcnt

            // ---- compute: kh = i, 3 kw taps, 96 MFMAs/wave ----
            const int r = wp + i;
            __builtin_amdgcn_s_setprio(1);
            #pragma unroll
            for (int t = 0; t < 3; ++t) {
                const bf16_t* abuf = cur + t * 8192;
                bf16x8 af[8];
                #pragma unroll
                for (int of = 0; of < 8; ++of)
                    af[of] = *(const bf16x8*)&abuf[kg * 2048 + (wo * 128 + of * 16 + l15) * 8];

                bf16x8 bfr[4];
                #pragma unroll
                for (int nf = 0; nf < 4; ++nf) {
                    const int c = nf * 16 + l15 + t - 1;
                    if ((unsigned)c < 64u) {
                        const bf16_t* p = &lds_b[(r * 64 + c) * CPAD + k0];
                        bf16x4 lo = *(const bf16x4*)p;
                        bf16x4 hi = *(const bf16x4*)(p + 4);
                        bfr[nf] = __builtin_shufflevector(lo, hi, 0, 1, 2, 3, 4, 5, 6, 7);
                    } else {
                        bfr[nf] = bzero;     // horizontal zero-pad
                    }
                }

                #pragma unroll
                for (int of = 0; of < 8; ++of)
                    #pragma unroll
                    for (int nf = 0; nf < 4; ++nf)
                        acc[of][nf] = __builtin_amdgcn_mfma_f32_16x16x32_bf16(
                            af[of], bfr[nf], acc[of][nf], 0, 0, 0);
            }
            __builtin_amdgcn_s_setprio(0);

            if (i < 2)
                __builtin_amdgcn_s_barrier();   // phase boundary
        }

        if (ch < 7) {
            __builtin_amdgcn_s_barrier();       // all waves done reading lds_b
            BWRITE();                           // waits x-loads (compiler vmcnt)
            asm volatile("s_waitcnt lgkmcnt(0)" ::: "memory");
            __builtin_amdgcn_sched_barrier(0);
            __builtin_amdgcn_s_barrier();       // lds_b ready for next chunk
        }
    }
    #undef SUPER

    // ---- demod d for all 256 o's (fused prep2) ----
    __syncthreads();                             // lds_b reads done; reuse as d_sh
    float* d_sh = (float*)&lds_b[0];
    {
        const int ol   = tid >> 1;               // 0..255
        const int half = tid & 1;
        const float* wq_p = wsq + (size_t)ol * NC + half * 128;
        const float* sb   = s_buf + batch * NC + half * 128;
        float sum = 0.f;
        #pragma unroll 4
        for (int i = 0; i < 128; i += 4) {
            float4 w4 = *(const float4*)(wq_p + i);
            float4 s4 = *(const float4*)(sb + i);
            sum += w4.x * s4.x * s4.x + w4.y * s4.y * s4.y
                 + w4.z * s4.z * s4.z + w4.w * s4.w * s4.w;
        }
        sum += __shfl_xor(sum, 1);
        if (half == 0) d_sh[ol] = rsqrtf(sum + 1e-8f);
    }
    __syncthreads();

    // ---- epilogue: y = acc * d[b,o], store fp32 ----
    const int prow_g = row0 + wp;                // this wave's global image row
    #pragma unroll
    for (int of = 0; of < 8; ++of) {
        #pragma unroll
        for (int rg = 0; rg < 4; ++rg) {
            const int o_l = wo * 128 + of * 16 + kg * 4 + rg;
            const float dv = d_sh[o_l];
            const size_t obase = (size_t)(batch * NO + o_l) * NPIX;
            #pragma unroll
            for (int nf = 0; nf < 4; ++nf) {
                const int p_g = prow_g * 64 + nf * 16 + l15;
                out[obase + p_g] = acc[of][nf][rg] * dv;
            }
        }
    }
}

// ---------------------------------------------------------------------------
extern "C" void kernel_launch(void* const* d_in, const int* in_sizes, int n_in,
                              void* d_out, int out_size, void* d_ws, size_t ws_size,
                              hipStream_t stream)
{
    const float* x      = (const float*)d_in[0];
    const float* style  = (const float*)d_in[1];
    const float* weight = (const float*)d_in[2];
    const float* mod_w  = (const float*)d_in[3];
    const float* mod_b  = (const float*)d_in[4];
    float* out = (float*)d_out;

    char* ws = (char*)d_ws;
    float*  s_buf = (float*)(ws + WS_S);
    float*  wsq   = (float*)(ws + WS_WSQ);
    bf16_t* wT    = (bf16_t*)(ws + WS_WT);

    hipLaunchKernelGGL(prep1, dim3(272), dim3(256), 0, stream,
                       style, weight, mod_w, mod_b, s_buf, wsq, wT);
    hipLaunchKernelGGL(conv_mfma, dim3(16, 1, 16), dim3(512), 0, stream,
                       x, wT, s_buf, wsq, out);
}